// Round 4
// baseline (1358.305 us; speedup 1.0000x reference)
//
#include <hip/hip_runtime.h>
#include <hip/hip_bf16.h>

#define SEQ      1024
#define BATCH    4
#define NHEADS   16
#define HDIM     64
#define DMODEL   1024
#define DGRAPH   8
#define QK_SCALE 0.125f
#define PCONST   0.0009765625f   /* 1/1024 exact */

// ---------------------------------------------------------------------------
// Projection GEMM (unchanged from passing round): C = X * W^T + bias
// ---------------------------------------------------------------------------
template<int HEADSPLIT>
__global__ __launch_bounds__(256) void proj_gemm(
    const float* __restrict__ X,
    const float* __restrict__ W,
    const float* __restrict__ bias,
    float* __restrict__ Y)
{
    __shared__ float At[16][132];
    __shared__ float Bt[16][68];

    const int t  = threadIdx.x;
    const int tx = t & 15;
    const int ty = t >> 4;
    const int m0 = blockIdx.y * 128;
    const int c0 = blockIdx.x * 64;

    float acc[8][4];
#pragma unroll
    for (int i = 0; i < 8; ++i)
#pragma unroll
        for (int j = 0; j < 4; ++j) acc[i][j] = 0.f;

    for (int kt = 0; kt < 64; ++kt) {
#pragma unroll
        for (int i = 0; i < 2; ++i) {
            int f4 = t + i * 256;
            int row = f4 >> 2;
            int kq  = f4 & 3;
            float4 v = *reinterpret_cast<const float4*>(
                X + (size_t)(m0 + row) * DMODEL + kt * 16 + kq * 4);
            At[kq * 4 + 0][row] = v.x; At[kq * 4 + 1][row] = v.y;
            At[kq * 4 + 2][row] = v.z; At[kq * 4 + 3][row] = v.w;
        }
        {
            int col = t >> 2;
            int kq  = t & 3;
            float4 v = *reinterpret_cast<const float4*>(
                W + (size_t)(c0 + col) * DMODEL + kt * 16 + kq * 4);
            Bt[kq * 4 + 0][col] = v.x; Bt[kq * 4 + 1][col] = v.y;
            Bt[kq * 4 + 2][col] = v.z; Bt[kq * 4 + 3][col] = v.w;
        }
        __syncthreads();
#pragma unroll
        for (int k = 0; k < 16; ++k) {
            float4 a0 = *reinterpret_cast<const float4*>(&At[k][ty * 4]);
            float4 a1 = *reinterpret_cast<const float4*>(&At[k][64 + ty * 4]);
            float4 b0 = *reinterpret_cast<const float4*>(&Bt[k][tx * 4]);
            float av[8] = {a0.x, a0.y, a0.z, a0.w, a1.x, a1.y, a1.z, a1.w};
            float bv[4] = {b0.x, b0.y, b0.z, b0.w};
#pragma unroll
            for (int i = 0; i < 8; ++i)
#pragma unroll
                for (int j = 0; j < 4; ++j)
                    acc[i][j] = fmaf(av[i], bv[j], acc[i][j]);
        }
        __syncthreads();
    }

    float4 bv4 = *reinterpret_cast<const float4*>(bias + c0 + tx * 4);
    float bb[4] = {bv4.x, bv4.y, bv4.z, bv4.w};
    const int c = c0 + tx * 4;
#pragma unroll
    for (int i = 0; i < 8; ++i) {
        int r = m0 + ((i < 4) ? (ty * 4 + i) : (64 + ty * 4 + (i - 4)));
        float4 o;
        o.x = acc[i][0] + bb[0]; o.y = acc[i][1] + bb[1];
        o.z = acc[i][2] + bb[2]; o.w = acc[i][3] + bb[3];
        if (HEADSPLIT) {
            int b_ = r >> 10, n = r & 1023;
            int h = c >> 6, d = c & 63;
            *reinterpret_cast<float4*>(
                Y + ((size_t)((b_ * NHEADS + h) * SEQ + n)) * HDIM + d) = o;
        } else {
            *reinterpret_cast<float4*>(Y + (size_t)r * DMODEL + c) = o;
        }
    }
}

// ---------------------------------------------------------------------------
// Fused bias + QK^T: one block owns (b, 32 n-rows, 64 m-cols, ALL 16 heads).
// dists tile held in registers (read once from HBM, only for unmasked rows),
// reused by all 16 heads. S = bias + (Q*scale).K written only for unmasked
// rows into attL[bh][n][m]. Masked rows are never written (handled later).
// Thread layout: tn = t>>4 (2 rows each), tm = t&15 (4 m-cols each).
// ---------------------------------------------------------------------------
__global__ __launch_bounds__(256) void bias_qk_kernel(
    const float* __restrict__ QH,
    const float* __restrict__ KH,
    const float* __restrict__ dists,
    const float* __restrict__ wg,
    const int* __restrict__ mask,
    float* __restrict__ attL)
{
    __shared__ float Qs[32][65];     // [n][d], pad 65 -> 2-way max on reads
    __shared__ float Ks[64][65];     // [m][d]
    __shared__ float wgs[NHEADS * DGRAPH];
    __shared__ int   maskS[32];

    const int t  = threadIdx.x;
    const int tn = t >> 4;           // 0..15 -> rows tn*2, tn*2+1
    const int tm = t & 15;           // 0..15 -> cols tm*4..+3
    const int n0 = blockIdx.x * 32;  // n fastest: consecutive blocks share K tile
    const int m0 = blockIdx.y * 64;
    const int b  = blockIdx.z;

    if (t < NHEADS * DGRAPH) wgs[t] = wg[t];
    if (t < 32) maskS[t] = mask[b * SEQ + n0 + t];
    __syncthreads();

    // dists tile -> registers (zero for masked rows; never stored for them)
    float dreg[2][4][8];
#pragma unroll
    for (int r = 0; r < 2; ++r)
#pragma unroll
        for (int c = 0; c < 4; ++c)
#pragma unroll
            for (int p = 0; p < 8; ++p) dreg[r][c][p] = 0.f;

#pragma unroll
    for (int r = 0; r < 2; ++r) {
        int rr = tn * 2 + r;
        if (!maskS[rr]) {
            const float* dp = dists +
                (((size_t)(b * SEQ + n0 + rr)) * SEQ + m0 + tm * 4) * DGRAPH;
#pragma unroll
            for (int c = 0; c < 4; ++c) {
                float4 lo = *reinterpret_cast<const float4*>(dp + c * 8);
                float4 hi = *reinterpret_cast<const float4*>(dp + c * 8 + 4);
                dreg[r][c][0] = lo.x; dreg[r][c][1] = lo.y;
                dreg[r][c][2] = lo.z; dreg[r][c][3] = lo.w;
                dreg[r][c][4] = hi.x; dreg[r][c][5] = hi.y;
                dreg[r][c][6] = hi.z; dreg[r][c][7] = hi.w;
            }
        }
    }

    for (int h = 0; h < NHEADS; ++h) {
        const int bh = b * NHEADS + h;
        // stage Q (pre-scaled by QK_SCALE, exact pow2) and K
#pragma unroll
        for (int i = 0; i < 2; ++i) {
            int f4 = t + i * 256;
            int row = f4 >> 4, dq = f4 & 15;
            float4 q = *reinterpret_cast<const float4*>(
                QH + ((size_t)bh * SEQ + n0 + row) * HDIM + dq * 4);
            q.x *= QK_SCALE; q.y *= QK_SCALE; q.z *= QK_SCALE; q.w *= QK_SCALE;
            *reinterpret_cast<float4*>(&Qs[row][dq * 4]) = q;
        }
#pragma unroll
        for (int i = 0; i < 4; ++i) {
            int f4 = t + i * 256;
            int row = f4 >> 4, dq = f4 & 15;
            *reinterpret_cast<float4*>(&Ks[row][dq * 4]) =
                *reinterpret_cast<const float4*>(
                    KH + ((size_t)bh * SEQ + m0 + row) * HDIM + dq * 4);
        }
        __syncthreads();

        // init acc with graph bias (dreg is 0 for masked rows -> harmless)
        float4 w0 = *reinterpret_cast<const float4*>(&wgs[h * 8]);
        float4 w1 = *reinterpret_cast<const float4*>(&wgs[h * 8 + 4]);
        float wv[8] = {w0.x, w0.y, w0.z, w0.w, w1.x, w1.y, w1.z, w1.w};
        float acc[2][4];
#pragma unroll
        for (int r = 0; r < 2; ++r)
#pragma unroll
            for (int c = 0; c < 4; ++c) {
                float s = 0.f;
#pragma unroll
                for (int p = 0; p < 8; ++p)
                    s = fmaf(dreg[r][c][p], wv[p], s);
                acc[r][c] = s;
            }

        // QK^T accumulate
#pragma unroll
        for (int d4 = 0; d4 < 16; ++d4) {
            float4 qa0 = *reinterpret_cast<const float4*>(&Qs[tn * 2 + 0][d4 * 4]);
            float4 qa1 = *reinterpret_cast<const float4*>(&Qs[tn * 2 + 1][d4 * 4]);
            float qv[2][4] = {{qa0.x, qa0.y, qa0.z, qa0.w},
                              {qa1.x, qa1.y, qa1.z, qa1.w}};
#pragma unroll
            for (int c = 0; c < 4; ++c) {
                float4 kb = *reinterpret_cast<const float4*>(&Ks[tm * 4 + c][d4 * 4]);
                float kv[4] = {kb.x, kb.y, kb.z, kb.w};
#pragma unroll
                for (int r = 0; r < 2; ++r) {
                    acc[r][c] = fmaf(qv[r][0], kv[0], acc[r][c]);
                    acc[r][c] = fmaf(qv[r][1], kv[1], acc[r][c]);
                    acc[r][c] = fmaf(qv[r][2], kv[2], acc[r][c]);
                    acc[r][c] = fmaf(qv[r][3], kv[3], acc[r][c]);
                }
            }
        }

        // store S (unmasked rows only)
#pragma unroll
        for (int r = 0; r < 2; ++r) {
            int rr = tn * 2 + r;
            if (!maskS[rr]) {
                float4 o;
                o.x = acc[r][0]; o.y = acc[r][1]; o.z = acc[r][2]; o.w = acc[r][3];
                *reinterpret_cast<float4*>(
                    attL + ((size_t)bh * SEQ + n0 + rr) * SEQ + m0 + tm * 4) = o;
            }
        }
        __syncthreads();
    }
}

// ---------------------------------------------------------------------------
// Softmax (S -> p in-place in attL) + PV -> AO[b][n][h*64+d]
// 128 threads, 128 rows per block, 8x8 register tile (LDS-balanced: 1 B/FMA).
// Masked rows: no S read, p = 1/1024 exactly. XOR-swizzled p tile in LDS.
// S-loads for chunk k+1 prefetched into regs under chunk k's FMAs.
// ---------------------------------------------------------------------------
__global__ __launch_bounds__(128) void softmax_pv_kernel(
    float* __restrict__ attL,
    const float* __restrict__ VH,
    const int* __restrict__ mask,
    float* __restrict__ AO)
{
    __shared__ float pS[128 * 32];   // swizzled [row][32-m chunk], 16 KB
    __shared__ float Vs[32][68];     // [m][d]
    __shared__ float rowMax[128];
    __shared__ float rowInv[128];
    __shared__ int   maskS[128];

    const int t    = threadIdx.x;
    const int lane = t & 63;
    const int w    = t >> 6;         // 0..1
    const int n0   = blockIdx.x * 128;
    const int h    = blockIdx.y;
    const int b    = blockIdx.z;
    const int bh   = b * NHEADS + h;
    float* Lbase = attL + ((size_t)bh * SEQ + n0) * SEQ;

    if (t < 128) maskS[t] = mask[b * SEQ + n0 + t];
    __syncthreads();

    // ---- Phase A: per-row max & exp-sum (unmasked rows only) ----
    for (int rr = 0; rr < 64; ++rr) {
        int r = w * 64 + rr;
        if (maskS[r]) continue;
        const float* rp = Lbase + (size_t)r * SEQ;
        float rv[16];
#pragma unroll
        for (int i = 0; i < 4; ++i) {
            float4 v = *reinterpret_cast<const float4*>(rp + i * 256 + lane * 4);
            rv[i * 4 + 0] = v.x; rv[i * 4 + 1] = v.y;
            rv[i * 4 + 2] = v.z; rv[i * 4 + 3] = v.w;
        }
        float mx = rv[0];
#pragma unroll
        for (int i = 1; i < 16; ++i) mx = fmaxf(mx, rv[i]);
#pragma unroll
        for (int off = 32; off >= 1; off >>= 1) mx = fmaxf(mx, __shfl_xor(mx, off));
        float s = 0.f;
#pragma unroll
        for (int i = 0; i < 16; ++i) s += __expf(rv[i] - mx);
#pragma unroll
        for (int off = 32; off >= 1; off >>= 1) s += __shfl_xor(s, off);
        if (lane == 0) { rowMax[r] = mx; rowInv[r] = 1.0f / s; }
    }
    __syncthreads();

    // ---- Phase B: p + PV, 32 chunks of 32 m ----
    const int TX = t & 7;            // d = TX*8 .. +7
    const int TY = t >> 3;           // rows TY*8 .. +7
    float acc[8][8];
#pragma unroll
    for (int i = 0; i < 8; ++i)
#pragma unroll
        for (int d = 0; d < 8; ++d) acc[i][d] = 0.f;

    float4 sreg[8];
#pragma unroll
    for (int i = 0; i < 8; ++i) sreg[i] = make_float4(0.f, 0.f, 0.f, 0.f);

    // prefetch chunk 0
#pragma unroll
    for (int i = 0; i < 8; ++i) {
        int f4 = t + i * 128;
        int row = f4 >> 3, mq = f4 & 7;
        if (!maskS[row])
            sreg[i] = *reinterpret_cast<const float4*>(
                Lbase + (size_t)row * SEQ + mq * 4);
    }

    for (int mc = 0; mc < 32; ++mc) {
        // produce p for this chunk: global att write + swizzled LDS write
#pragma unroll
        for (int i = 0; i < 8; ++i) {
            int f4 = t + i * 128;
            int row = f4 >> 3, mq = f4 & 7;
            float4 p4;
            if (maskS[row]) {
                p4.x = PCONST; p4.y = PCONST; p4.z = PCONST; p4.w = PCONST;
            } else {
                float mx = rowMax[row], iv = rowInv[row];
                p4.x = __expf(sreg[i].x - mx) * iv;
                p4.y = __expf(sreg[i].y - mx) * iv;
                p4.z = __expf(sreg[i].z - mx) * iv;
                p4.w = __expf(sreg[i].w - mx) * iv;
            }
            *reinterpret_cast<float4*>(
                Lbase + (size_t)row * SEQ + mc * 32 + mq * 4) = p4;
            *reinterpret_cast<float4*>(
                pS + row * 32 + ((mq ^ ((row >> 3) & 7)) << 2)) = p4;
        }
        // stage V chunk [32][64]
#pragma unroll
        for (int i = 0; i < 4; ++i) {
            int f4 = t + i * 128;
            int m = f4 >> 4, dq = f4 & 15;
            *reinterpret_cast<float4*>(&Vs[m][dq * 4]) =
                *reinterpret_cast<const float4*>(
                    VH + ((size_t)bh * SEQ + mc * 32 + m) * HDIM + dq * 4);
        }
        __syncthreads();

        // prefetch next chunk's S under this chunk's FMAs
        if (mc + 1 < 32) {
#pragma unroll
            for (int i = 0; i < 8; ++i) {
                int f4 = t + i * 128;
                int row = f4 >> 3, mq = f4 & 7;
                if (!maskS[row])
                    sreg[i] = *reinterpret_cast<const float4*>(
                        Lbase + (size_t)row * SEQ + (mc + 1) * 32 + mq * 4);
            }
        }

        // micro: 8 rows x 8 d, over 32 m
#pragma unroll
        for (int m4 = 0; m4 < 8; ++m4) {
            float pav[8][4];
            const int swz = (m4 ^ (TY & 7)) << 2;
#pragma unroll
            for (int i = 0; i < 8; ++i) {
                float4 p = *reinterpret_cast<const float4*>(
                    pS + (TY * 8 + i) * 32 + swz);
                pav[i][0] = p.x; pav[i][1] = p.y; pav[i][2] = p.z; pav[i][3] = p.w;
            }
#pragma unroll
            for (int j = 0; j < 4; ++j) {
                float4 v0 = *reinterpret_cast<const float4*>(&Vs[m4 * 4 + j][TX * 8]);
                float4 v1 = *reinterpret_cast<const float4*>(&Vs[m4 * 4 + j][TX * 8 + 4]);
                float vb[8] = {v0.x, v0.y, v0.z, v0.w, v1.x, v1.y, v1.z, v1.w};
#pragma unroll
                for (int i = 0; i < 8; ++i)
#pragma unroll
                    for (int d = 0; d < 8; ++d)
                        acc[i][d] = fmaf(pav[i][j], vb[d], acc[i][d]);
            }
        }
        __syncthreads();
    }

    // write AO rows (TY*8..+7) x cols (h*64 + TX*8..+7)
#pragma unroll
    for (int i = 0; i < 8; ++i) {
        int n = n0 + TY * 8 + i;
        float4 o0, o1;
        o0.x = acc[i][0]; o0.y = acc[i][1]; o0.z = acc[i][2]; o0.w = acc[i][3];
        o1.x = acc[i][4]; o1.y = acc[i][5]; o1.z = acc[i][6]; o1.w = acc[i][7];
        float* op = AO + ((size_t)(b * SEQ + n)) * DMODEL + h * HDIM + TX * 8;
        *reinterpret_cast<float4*>(op)     = o0;
        *reinterpret_cast<float4*>(op + 4) = o1;
    }
}

// ---------------------------------------------------------------------------
extern "C" void kernel_launch(void* const* d_in, const int* in_sizes, int n_in,
                              void* d_out, int out_size, void* d_ws, size_t ws_size,
                              hipStream_t stream) {
    const float* q       = (const float*)d_in[0];
    const float* k       = (const float*)d_in[1];
    const float* v       = (const float*)d_in[2];
    const int*   mask    = (const int*)d_in[3];
    const float* dists   = (const float*)d_in[4];
    const float* weights = (const float*)d_in[5];
    const float* biases  = (const float*)d_in[6];
    const float* wg      = (const float*)d_in[7];

    float* out  = (float*)d_out;
    float* attL = out + (size_t)BATCH * SEQ * DMODEL;          // att region of d_out

    float* ws = (float*)d_ws;
    const size_t HSZ = (size_t)BATCH * NHEADS * SEQ * HDIM;    // 4M floats
    float* QH = ws;
    float* KH = ws + HSZ;
    float* VH = ws + 2 * HSZ;
    float* AO = ws;   // aliases QH: QH dead after bias_qk (stream-ordered)

    dim3 gProj(DMODEL / 64, (BATCH * SEQ) / 128);              // (16, 32)
    proj_gemm<1><<<gProj, 256, 0, stream>>>(q, weights, biases, QH);
    proj_gemm<1><<<gProj, 256, 0, stream>>>(k, weights + 1 * (size_t)DMODEL * DMODEL,
                                            biases + DMODEL, KH);
    proj_gemm<1><<<gProj, 256, 0, stream>>>(v, weights + 2 * (size_t)DMODEL * DMODEL,
                                            biases + 2 * DMODEL, VH);

    dim3 gBQ(SEQ / 32, SEQ / 64, BATCH);                       // (32, 16, 4)
    bias_qk_kernel<<<gBQ, 256, 0, stream>>>(QH, KH, dists, wg, mask, attL);

    dim3 gPV(SEQ / 128, NHEADS, BATCH);                        // (8, 16, 4)
    softmax_pv_kernel<<<gPV, 128, 0, stream>>>(attL, VH, mask, AO);

    proj_gemm<0><<<gProj, 256, 0, stream>>>(AO, weights + 3 * (size_t)DMODEL * DMODEL,
                                            biases + 3 * DMODEL, out);
}

// Round 5
// 516.708 us; speedup vs baseline: 2.6288x; 2.6288x over previous
//
#include <hip/hip_runtime.h>
#include <hip/hip_bf16.h>

#define SEQ      1024
#define BATCH    4
#define NHEADS   16
#define HDIM     64
#define DMODEL   1024
#define DGRAPH   8
#define QK_SCALE 0.125f
#define PCONST   0.0009765625f   /* 1/1024 exact */
#define NEG_INF  (-1.0e9f)

typedef __attribute__((ext_vector_type(8))) short bf16x8;
typedef __attribute__((ext_vector_type(4))) float f32x4;

__device__ __forceinline__ void split_bf16(float x, short& hi, short& lo) {
    unsigned u = __float_as_uint(x);
    hi = (short)(u >> 16);                         // truncated high part
    float hf = __uint_as_float(u & 0xffff0000u);
    lo = (short)(__float_as_uint(x - hf) >> 16);   // residual, truncated
}

// ---------------------------------------------------------------------------
// Split-bf16 MFMA projection: C[4096][1024] = X * W^T + bias.
// W row-major [n][k]. BM=128, BN=64, BK=32. 256 threads = 4 waves (2x2),
// wave sub-tile 64x32 = 4x2 fragments of 16x16. Per wave-K-step:
// 24 MFMA : 12 ds_read_b128. LDS rows padded to 40 bf16 (80 B) -> 2-way max.
// Error model: hi*hi + hi*lo + lo*hi drops only the ~2^-18 lo*lo term.
// ---------------------------------------------------------------------------
template<int HEADSPLIT>
__global__ __launch_bounds__(256) void proj_mfma(
    const float* __restrict__ X,
    const float* __restrict__ W,
    const float* __restrict__ bias,
    float* __restrict__ Y)
{
    constexpr int LDK = 40;
    __shared__ short Ah[128 * LDK];
    __shared__ short Al[128 * LDK];
    __shared__ short Bh[64 * LDK];
    __shared__ short Bl[64 * LDK];

    const int t   = threadIdx.x;
    const int w   = t >> 6;
    const int l   = t & 63;
    const int l15 = l & 15;
    const int lk  = (l >> 4) * 8;          // k-offset of this lane's fragment
    const int m0  = blockIdx.y * 128;
    const int c0  = blockIdx.x * 64;
    const int wr  = (w >> 1) * 64;         // wave row base within tile
    const int wc  = (w & 1) * 32;          // wave col base within tile

    const int srow = t >> 2;               // staging helpers: 4 k-groups/row
    const int skg  = t & 3;                // k-group (8 k each)

    f32x4 acc[4][2];
#pragma unroll
    for (int i = 0; i < 4; ++i)
#pragma unroll
        for (int j = 0; j < 2; ++j) acc[i][j] = f32x4{0.f, 0.f, 0.f, 0.f};

    float xa[2][8];
    float wa[8];

    // prologue: load K-tile 0 into registers
#pragma unroll
    for (int i = 0; i < 2; ++i) {
        const float* p = X + (size_t)(m0 + srow + i * 64) * DMODEL + skg * 8;
        float4 u0 = *(const float4*)p;
        float4 u1 = *(const float4*)(p + 4);
        xa[i][0] = u0.x; xa[i][1] = u0.y; xa[i][2] = u0.z; xa[i][3] = u0.w;
        xa[i][4] = u1.x; xa[i][5] = u1.y; xa[i][6] = u1.z; xa[i][7] = u1.w;
    }
    {
        const float* p = W + (size_t)(c0 + srow) * DMODEL + skg * 8;
        float4 u0 = *(const float4*)p;
        float4 u1 = *(const float4*)(p + 4);
        wa[0] = u0.x; wa[1] = u0.y; wa[2] = u0.z; wa[3] = u0.w;
        wa[4] = u1.x; wa[5] = u1.y; wa[6] = u1.z; wa[7] = u1.w;
    }

    for (int kt = 0; kt < 32; ++kt) {
        // convert + stage current tile
#pragma unroll
        for (int i = 0; i < 2; ++i) {
            bf16x8 hv, lv;
#pragma unroll
            for (int j = 0; j < 8; ++j) {
                short h, s; split_bf16(xa[i][j], h, s);
                hv[j] = h; lv[j] = s;
            }
            *(bf16x8*)(Ah + (srow + i * 64) * LDK + skg * 8) = hv;
            *(bf16x8*)(Al + (srow + i * 64) * LDK + skg * 8) = lv;
        }
        {
            bf16x8 hv, lv;
#pragma unroll
            for (int j = 0; j < 8; ++j) {
                short h, s; split_bf16(wa[j], h, s);
                hv[j] = h; lv[j] = s;
            }
            *(bf16x8*)(Bh + srow * LDK + skg * 8) = hv;
            *(bf16x8*)(Bl + srow * LDK + skg * 8) = lv;
        }
        __syncthreads();

        // prefetch next K-tile (hides HBM latency under MFMAs)
        if (kt + 1 < 32) {
            const int k0 = (kt + 1) * 32;
#pragma unroll
            for (int i = 0; i < 2; ++i) {
                const float* p = X + (size_t)(m0 + srow + i * 64) * DMODEL + k0 + skg * 8;
                float4 u0 = *(const float4*)p;
                float4 u1 = *(const float4*)(p + 4);
                xa[i][0] = u0.x; xa[i][1] = u0.y; xa[i][2] = u0.z; xa[i][3] = u0.w;
                xa[i][4] = u1.x; xa[i][5] = u1.y; xa[i][6] = u1.z; xa[i][7] = u1.w;
            }
            const float* p = W + (size_t)(c0 + srow) * DMODEL + k0 + skg * 8;
            float4 u0 = *(const float4*)p;
            float4 u1 = *(const float4*)(p + 4);
            wa[0] = u0.x; wa[1] = u0.y; wa[2] = u0.z; wa[3] = u0.w;
            wa[4] = u1.x; wa[5] = u1.y; wa[6] = u1.z; wa[7] = u1.w;
        }

        // fragments + MFMA
        bf16x8 ah[4], alo[4], bh[2], blo[2];
#pragma unroll
        for (int fm = 0; fm < 4; ++fm) {
            const int off = (wr + fm * 16 + l15) * LDK + lk;
            ah[fm]  = *(const bf16x8*)(Ah + off);
            alo[fm] = *(const bf16x8*)(Al + off);
        }
#pragma unroll
        for (int fn = 0; fn < 2; ++fn) {
            const int off = (wc + fn * 16 + l15) * LDK + lk;
            bh[fn]  = *(const bf16x8*)(Bh + off);
            blo[fn] = *(const bf16x8*)(Bl + off);
        }
#pragma unroll
        for (int fm = 0; fm < 4; ++fm)
#pragma unroll
            for (int fn = 0; fn < 2; ++fn) {
                acc[fm][fn] = __builtin_amdgcn_mfma_f32_16x16x32_bf16(
                    ah[fm], bh[fn], acc[fm][fn], 0, 0, 0);
                acc[fm][fn] = __builtin_amdgcn_mfma_f32_16x16x32_bf16(
                    ah[fm], blo[fn], acc[fm][fn], 0, 0, 0);
                acc[fm][fn] = __builtin_amdgcn_mfma_f32_16x16x32_bf16(
                    alo[fm], bh[fn], acc[fm][fn], 0, 0, 0);
            }
        __syncthreads();
    }

    // epilogue: C/D layout col = l&15, row = (l>>4)*4 + r  [verified m89/m91]
#pragma unroll
    for (int fm = 0; fm < 4; ++fm)
#pragma unroll
        for (int fn = 0; fn < 2; ++fn) {
            const int c = c0 + wc + fn * 16 + l15;
            const float bb = bias[c];
#pragma unroll
            for (int r = 0; r < 4; ++r) {
                const int m = m0 + wr + fm * 16 + (l >> 4) * 4 + r;
                const float v = acc[fm][fn][r] + bb;
                if (HEADSPLIT) {
                    const int b_ = m >> 10, n = m & 1023;
                    const int h = c >> 6, d = c & 63;
                    Y[((size_t)((b_ * NHEADS + h) * SEQ + n)) * HDIM + d] = v;
                } else {
                    Y[(size_t)m * DMODEL + c] = v;
                }
            }
        }
}

// ---------------------------------------------------------------------------
// Graph bias: attL[b][h][n][m] = dists[b][n][m][:8] . wg[h][:8]
// One block per (b,n); block-uniform early exit for masked rows.
// ---------------------------------------------------------------------------
__global__ __launch_bounds__(256) void graph_bias_kernel(
    const float* __restrict__ dists,
    const float* __restrict__ wg,
    const int* __restrict__ mask,
    float* __restrict__ attL)
{
    const int n = blockIdx.x & 1023;
    const int b = blockIdx.x >> 10;
    if (mask[b * SEQ + n]) return;

    __shared__ float wgs[NHEADS * DGRAPH];
    const int t = threadIdx.x;
    if (t < NHEADS * DGRAPH) wgs[t] = wg[t];
    __syncthreads();

    const int m = t * 4;
    const float* dp = dists + (((size_t)(b * SEQ + n)) * SEQ + m) * DGRAPH;
    float d[4][8];
#pragma unroll
    for (int i = 0; i < 8; ++i) {
        float4 v = *reinterpret_cast<const float4*>(dp + i * 4);
        d[i >> 1][(i & 1) * 4 + 0] = v.x; d[i >> 1][(i & 1) * 4 + 1] = v.y;
        d[i >> 1][(i & 1) * 4 + 2] = v.z; d[i >> 1][(i & 1) * 4 + 3] = v.w;
    }
#pragma unroll
    for (int h = 0; h < NHEADS; ++h) {
        float ov[4];
#pragma unroll
        for (int jm = 0; jm < 4; ++jm) {
            float s = 0.f;
#pragma unroll
            for (int p = 0; p < DGRAPH; ++p)
                s = fmaf(d[jm][p], wgs[h * DGRAPH + p], s);
            ov[jm] = s;
        }
        float4 o; o.x = ov[0]; o.y = ov[1]; o.z = ov[2]; o.w = ov[3];
        *reinterpret_cast<float4*>(
            attL + (((size_t)((b * NHEADS + h) * SEQ + n)) * SEQ + m)) = o;
    }
}

// ---------------------------------------------------------------------------
// QK^T: attL[bh][n][m] += (Q.K)*SCALE  (RMW of staged bias; unmasked rows only;
// masked rows never read nor written — softmax emits PCONST for them).
// Per (b,h): 128x128 tile, full Dh=64 inner, 8x8 micro.
// ---------------------------------------------------------------------------
__global__ __launch_bounds__(256) void qk_kernel(
    const float* __restrict__ QH,
    const float* __restrict__ KH,
    const int* __restrict__ mask,
    float* __restrict__ attL)
{
    __shared__ float QT[64][132];  // [d][n]
    __shared__ float KT[64][132];  // [d][m]
    __shared__ int maskS[128];

    const int t  = threadIdx.x;
    const int tx = t & 15;
    const int ty = t >> 4;
    const int m0 = blockIdx.x * 128;
    const int n0 = blockIdx.y * 128;
    const int bh = blockIdx.z;
    const int b  = bh >> 4;

    const float* Qbase = QH + ((size_t)bh * SEQ + n0) * HDIM;
    const float* Kbase = KH + ((size_t)bh * SEQ + m0) * HDIM;
    if (t < 128) maskS[t] = mask[b * SEQ + n0 + t];

#pragma unroll
    for (int i = 0; i < 8; ++i) {
        int f4 = t + i * 256;
        int row = f4 >> 4;
        int dq  = f4 & 15;
        float4 q = *reinterpret_cast<const float4*>(Qbase + (size_t)row * HDIM + dq * 4);
        QT[dq * 4 + 0][row] = q.x; QT[dq * 4 + 1][row] = q.y;
        QT[dq * 4 + 2][row] = q.z; QT[dq * 4 + 3][row] = q.w;
        float4 kv = *reinterpret_cast<const float4*>(Kbase + (size_t)row * HDIM + dq * 4);
        KT[dq * 4 + 0][row] = kv.x; KT[dq * 4 + 1][row] = kv.y;
        KT[dq * 4 + 2][row] = kv.z; KT[dq * 4 + 3][row] = kv.w;
    }
    __syncthreads();

    float acc[8][8];
#pragma unroll
    for (int i = 0; i < 8; ++i)
#pragma unroll
        for (int j = 0; j < 8; ++j) acc[i][j] = 0.f;

#pragma unroll 8
    for (int d = 0; d < 64; ++d) {
        float4 a0 = *reinterpret_cast<const float4*>(&QT[d][ty * 4]);
        float4 a1 = *reinterpret_cast<const float4*>(&QT[d][64 + ty * 4]);
        float4 b0 = *reinterpret_cast<const float4*>(&KT[d][tx * 4]);
        float4 b1 = *reinterpret_cast<const float4*>(&KT[d][64 + tx * 4]);
        float av[8] = {a0.x, a0.y, a0.z, a0.w, a1.x, a1.y, a1.z, a1.w};
        float bv[8] = {b0.x, b0.y, b0.z, b0.w, b1.x, b1.y, b1.z, b1.w};
#pragma unroll
        for (int i = 0; i < 8; ++i)
#pragma unroll
            for (int j = 0; j < 8; ++j)
                acc[i][j] = fmaf(av[i], bv[j], acc[i][j]);
    }

#pragma unroll
    for (int i = 0; i < 8; ++i) {
        int ri = (i < 4) ? (ty * 4 + i) : (64 + ty * 4 + (i - 4));
        if (maskS[ri]) continue;
        int n = n0 + ri;
        float* rowp = attL + ((size_t)bh * SEQ + n) * SEQ + m0;
#pragma unroll
        for (int jg = 0; jg < 2; ++jg) {
            int coff = jg * 64 + tx * 4;
            float4 old = *reinterpret_cast<const float4*>(rowp + coff);
            float4 o;
            o.x = fmaf(acc[i][jg * 4 + 0], QK_SCALE, old.x);
            o.y = fmaf(acc[i][jg * 4 + 1], QK_SCALE, old.y);
            o.z = fmaf(acc[i][jg * 4 + 2], QK_SCALE, old.z);
            o.w = fmaf(acc[i][jg * 4 + 3], QK_SCALE, old.w);
            *reinterpret_cast<float4*>(rowp + coff) = o;
        }
    }
}

// ---------------------------------------------------------------------------
// Softmax (S -> p in-place) + PV -> AO. 256 threads, 128 rows/block.
// Masked rows: p = 1/1024 exact, no S read. Swizzled p tile; S prefetch
// under FMAs. 4 waves/block (vs round-4's 2) for latency hiding.
// ---------------------------------------------------------------------------
__global__ __launch_bounds__(256) void softmax_pv_kernel(
    float* __restrict__ attL,
    const float* __restrict__ VH,
    const int* __restrict__ mask,
    float* __restrict__ AO)
{
    __shared__ float pS[128 * 32];
    __shared__ float Vs[32][68];
    __shared__ float rowMax[128];
    __shared__ float rowInv[128];
    __shared__ int   maskS[128];

    const int t    = threadIdx.x;
    const int lane = t & 63;
    const int w    = t >> 6;          // 0..3
    const int n0   = blockIdx.x * 128;
    const int h    = blockIdx.y;
    const int b    = blockIdx.z;
    const int bh   = b * NHEADS + h;
    float* Lbase = attL + ((size_t)bh * SEQ + n0) * SEQ;

    if (t < 128) maskS[t] = mask[b * SEQ + n0 + t];
    __syncthreads();

    // ---- Phase A: per-row max & exp-sum (4 waves x 32 rows) ----
    for (int rr = 0; rr < 32; ++rr) {
        int r = w * 32 + rr;
        if (maskS[r]) continue;
        const float* rp = Lbase + (size_t)r * SEQ;
        float rv[16];
#pragma unroll
        for (int i = 0; i < 4; ++i) {
            float4 v = *reinterpret_cast<const float4*>(rp + i * 256 + lane * 4);
            rv[i * 4 + 0] = v.x; rv[i * 4 + 1] = v.y;
            rv[i * 4 + 2] = v.z; rv[i * 4 + 3] = v.w;
        }
        float mx = rv[0];
#pragma unroll
        for (int i = 1; i < 16; ++i) mx = fmaxf(mx, rv[i]);
#pragma unroll
        for (int off = 32; off >= 1; off >>= 1) mx = fmaxf(mx, __shfl_xor(mx, off));
        float s = 0.f;
#pragma unroll
        for (int i = 0; i < 16; ++i) s += __expf(rv[i] - mx);
#pragma unroll
        for (int off = 32; off >= 1; off >>= 1) s += __shfl_xor(s, off);
        if (lane == 0) { rowMax[r] = mx; rowInv[r] = 1.0f / s; }
    }
    __syncthreads();

    // ---- Phase B: p + PV, 32 chunks of 32 m ----
    const int TX = t & 7;             // d = TX*8 .. +7
    const int TY = t >> 3;            // rows TY*4 .. +3
    float acc[4][8];
#pragma unroll
    for (int i = 0; i < 4; ++i)
#pragma unroll
        for (int d = 0; d < 8; ++d) acc[i][d] = 0.f;

    float4 sreg[4];
#pragma unroll
    for (int i = 0; i < 4; ++i) sreg[i] = make_float4(0.f, 0.f, 0.f, 0.f);

    // prefetch chunk 0
#pragma unroll
    for (int i = 0; i < 4; ++i) {
        int f4 = t + i * 256;
        int row = f4 >> 3, mq = f4 & 7;
        if (!maskS[row])
            sreg[i] = *reinterpret_cast<const float4*>(
                Lbase + (size_t)row * SEQ + mq * 4);
    }

    for (int mc = 0; mc < 32; ++mc) {
        // produce p: global att write + swizzled LDS write
#pragma unroll
        for (int i = 0; i < 4; ++i) {
            int f4 = t + i * 256;
            int row = f4 >> 3, mq = f4 & 7;
            float4 p4;
            if (maskS[row]) {
                p4.x = PCONST; p4.y = PCONST; p4.z = PCONST; p4.w = PCONST;
            } else {
                float mx = rowMax[row], iv = rowInv[row];
                p4.x = __expf(sreg[i].x - mx) * iv;
                p4.y = __expf(sreg[i].y - mx) * iv;
                p4.z = __expf(sreg[i].z - mx) * iv;
                p4.w = __expf(sreg[i].w - mx) * iv;
            }
            *reinterpret_cast<float4*>(
                Lbase + (size_t)row * SEQ + mc * 32 + mq * 4) = p4;
            *reinterpret_cast<float4*>(
                pS + row * 32 + ((mq ^ ((row >> 3) & 7)) << 2)) = p4;
        }
        // stage V chunk [32][64]
#pragma unroll
        for (int i = 0; i < 2; ++i) {
            int f4 = t + i * 256;
            int m = f4 >> 4, dq = f4 & 15;
            *reinterpret_cast<float4*>(&Vs[m][dq * 4]) =
                *reinterpret_cast<const float4*>(
                    VH + ((size_t)bh * SEQ + mc * 32 + m) * HDIM + dq * 4);
        }
        __syncthreads();

        // prefetch next chunk's S under this chunk's FMAs
        if (mc + 1 < 32) {
#pragma unroll
            for (int i = 0; i < 4; ++i) {
                int f4 = t + i * 256;
                int row = f4 >> 3, mq = f4 & 7;
                if (!maskS[row])
                    sreg[i] = *reinterpret_cast<const float4*>(
                        Lbase + (size_t)row * SEQ + (mc + 1) * 32 + mq * 4);
            }
        }

        // micro: 4 rows x 8 d over 32 m
#pragma unroll
        for (int m4 = 0; m4 < 8; ++m4) {
            float pav[4][4];
#pragma unroll
            for (int i = 0; i < 4; ++i) {
                int row = TY * 4 + i;
                float4 p = *reinterpret_cast<const float4*>(
                    pS + row * 32 + ((m4 ^ ((row >> 3) & 7)) << 2));
                pav[i][0] = p.x; pav[i][1] = p.y; pav[i][2] = p.z; pav[i][3] = p.w;
            }
#pragma unroll
            for (int j = 0; j < 4; ++j) {
                float4 v0 = *reinterpret_cast<const float4*>(&Vs[m4 * 4 + j][TX * 8]);
                float4 v1 = *reinterpret_cast<const float4*>(&Vs[m4 * 4 + j][TX * 8 + 4]);
                float vb[8] = {v0.x, v0.y, v0.z, v0.w, v1.x, v1.y, v1.z, v1.w};
#pragma unroll
                for (int i = 0; i < 4; ++i)
#pragma unroll
                    for (int d = 0; d < 8; ++d)
                        acc[i][d] = fmaf(pav[i][j], vb[d], acc[i][d]);
            }
        }
        __syncthreads();
    }

#pragma unroll
    for (int i = 0; i < 4; ++i) {
        int n = n0 + TY * 4 + i;
        float4 o0, o1;
        o0.x = acc[i][0]; o0.y = acc[i][1]; o0.z = acc[i][2]; o0.w = acc[i][3];
        o1.x = acc[i][4]; o1.y = acc[i][5]; o1.z = acc[i][6]; o1.w = acc[i][7];
        float* op = AO + ((size_t)(b * SEQ + n)) * DMODEL + h * HDIM + TX * 8;
        *reinterpret_cast<float4*>(op)     = o0;
        *reinterpret_cast<float4*>(op + 4) = o1;
    }
}

// ---------------------------------------------------------------------------
extern "C" void kernel_launch(void* const* d_in, const int* in_sizes, int n_in,
                              void* d_out, int out_size, void* d_ws, size_t ws_size,
                              hipStream_t stream) {
    const float* q       = (const float*)d_in[0];
    const float* k       = (const float*)d_in[1];
    const float* v       = (const float*)d_in[2];
    const int*   mask    = (const int*)d_in[3];
    const float* dists   = (const float*)d_in[4];
    const float* weights = (const float*)d_in[5];
    const float* biases  = (const float*)d_in[6];
    const float* wg      = (const float*)d_in[7];

    float* out  = (float*)d_out;
    float* attL = out + (size_t)BATCH * SEQ * DMODEL;          // att region of d_out

    float* ws = (float*)d_ws;
    const size_t HSZ = (size_t)BATCH * NHEADS * SEQ * HDIM;    // 4M floats
    float* QH = ws;
    float* KH = ws + HSZ;
    float* VH = ws + 2 * HSZ;
    float* AO = ws;   // aliases QH: QH dead after qk_kernel (stream-ordered)

    dim3 gProj(DMODEL / 64, (BATCH * SEQ) / 128);              // (16, 32)
    proj_mfma<1><<<gProj, 256, 0, stream>>>(q, weights, biases, QH);
    proj_mfma<1><<<gProj, 256, 0, stream>>>(k, weights + 1 * (size_t)DMODEL * DMODEL,
                                            biases + DMODEL, KH);
    proj_mfma<1><<<gProj, 256, 0, stream>>>(v, weights + 2 * (size_t)DMODEL * DMODEL,
                                            biases + 2 * DMODEL, VH);

    graph_bias_kernel<<<BATCH * SEQ, 256, 0, stream>>>(dists, wg, mask, attL);

    dim3 gQK(SEQ / 128, SEQ / 128, BATCH * NHEADS);            // (8, 8, 64)
    qk_kernel<<<gQK, 256, 0, stream>>>(QH, KH, mask, attL);

    dim3 gPV(SEQ / 128, NHEADS, BATCH);                        // (8, 16, 4)
    softmax_pv_kernel<<<gPV, 256, 0, stream>>>(attL, VH, mask, AO);

    proj_mfma<0><<<gProj, 256, 0, stream>>>(AO, weights + 3 * (size_t)DMODEL * DMODEL,
                                            biases + 3 * DMODEL, out);
}

// Round 6
// 476.820 us; speedup vs baseline: 2.8487x; 1.0837x over previous
//
#include <hip/hip_runtime.h>
#include <hip/hip_bf16.h>

#define SEQ      1024
#define BATCH    4
#define NHEADS   16
#define HDIM     64
#define DMODEL   1024
#define DGRAPH   8
#define QK_SCALE 0.125f
#define PCONST   0.0009765625f   /* 1/1024 exact */

typedef __attribute__((ext_vector_type(8))) short bf16x8;
typedef __attribute__((ext_vector_type(4))) float f32x4;

__device__ __forceinline__ void split_bf16(float x, short& hi, short& lo) {
    unsigned u = __float_as_uint(x);
    hi = (short)(u >> 16);                         // truncated high part
    float hf = __uint_as_float(u & 0xffff0000u);
    lo = (short)(__float_as_uint(x - hf) >> 16);   // residual, truncated
}

__global__ void zero_f32(float* p, int n) {
    int i = blockIdx.x * 256 + threadIdx.x;
    if (i < n) p[i] = 0.f;
}

// ---------------------------------------------------------------------------
// Split-bf16 MFMA projection: C[4096][1024] = X * W^T + bias (then *scale).
// OUTMODE 0: fp32 flat [m][DMODEL]   (final projection)
// OUTMODE 1: fp32 headsplit [b][h][n][d]            (V)
// OUTMODE 2: bf16 hi/lo headsplit    (Q pre-scaled, K)
// BM=128, BN=64, BK=32, 4 waves (2x2). Proven in round 5.
// ---------------------------------------------------------------------------
template<int OUTMODE>
__global__ __launch_bounds__(256) void proj_mfma(
    const float* __restrict__ X,
    const float* __restrict__ W,
    const float* __restrict__ bias,
    float* __restrict__ Yf,
    short* __restrict__ Yhi,
    short* __restrict__ Ylo,
    float scale)
{
    constexpr int LDK = 40;
    __shared__ short Ah[128 * LDK];
    __shared__ short Al[128 * LDK];
    __shared__ short Bh[64 * LDK];
    __shared__ short Bl[64 * LDK];

    const int t   = threadIdx.x;
    const int w   = t >> 6;
    const int l   = t & 63;
    const int l15 = l & 15;
    const int lk  = (l >> 4) * 8;
    const int m0  = blockIdx.y * 128;
    const int c0  = blockIdx.x * 64;
    const int wr  = (w >> 1) * 64;
    const int wc  = (w & 1) * 32;

    const int srow = t >> 2;
    const int skg  = t & 3;

    f32x4 acc[4][2];
#pragma unroll
    for (int i = 0; i < 4; ++i)
#pragma unroll
        for (int j = 0; j < 2; ++j) acc[i][j] = f32x4{0.f, 0.f, 0.f, 0.f};

    float xa[2][8];
    float wa[8];

#pragma unroll
    for (int i = 0; i < 2; ++i) {
        const float* p = X + (size_t)(m0 + srow + i * 64) * DMODEL + skg * 8;
        float4 u0 = *(const float4*)p;
        float4 u1 = *(const float4*)(p + 4);
        xa[i][0] = u0.x; xa[i][1] = u0.y; xa[i][2] = u0.z; xa[i][3] = u0.w;
        xa[i][4] = u1.x; xa[i][5] = u1.y; xa[i][6] = u1.z; xa[i][7] = u1.w;
    }
    {
        const float* p = W + (size_t)(c0 + srow) * DMODEL + skg * 8;
        float4 u0 = *(const float4*)p;
        float4 u1 = *(const float4*)(p + 4);
        wa[0] = u0.x; wa[1] = u0.y; wa[2] = u0.z; wa[3] = u0.w;
        wa[4] = u1.x; wa[5] = u1.y; wa[6] = u1.z; wa[7] = u1.w;
    }

    for (int kt = 0; kt < 32; ++kt) {
#pragma unroll
        for (int i = 0; i < 2; ++i) {
            bf16x8 hv, lv;
#pragma unroll
            for (int j = 0; j < 8; ++j) {
                short h, s; split_bf16(xa[i][j], h, s);
                hv[j] = h; lv[j] = s;
            }
            *(bf16x8*)(Ah + (srow + i * 64) * LDK + skg * 8) = hv;
            *(bf16x8*)(Al + (srow + i * 64) * LDK + skg * 8) = lv;
        }
        {
            bf16x8 hv, lv;
#pragma unroll
            for (int j = 0; j < 8; ++j) {
                short h, s; split_bf16(wa[j], h, s);
                hv[j] = h; lv[j] = s;
            }
            *(bf16x8*)(Bh + srow * LDK + skg * 8) = hv;
            *(bf16x8*)(Bl + srow * LDK + skg * 8) = lv;
        }
        __syncthreads();

        if (kt + 1 < 32) {
            const int k0 = (kt + 1) * 32;
#pragma unroll
            for (int i = 0; i < 2; ++i) {
                const float* p = X + (size_t)(m0 + srow + i * 64) * DMODEL + k0 + skg * 8;
                float4 u0 = *(const float4*)p;
                float4 u1 = *(const float4*)(p + 4);
                xa[i][0] = u0.x; xa[i][1] = u0.y; xa[i][2] = u0.z; xa[i][3] = u0.w;
                xa[i][4] = u1.x; xa[i][5] = u1.y; xa[i][6] = u1.z; xa[i][7] = u1.w;
            }
            const float* p = W + (size_t)(c0 + srow) * DMODEL + k0 + skg * 8;
            float4 u0 = *(const float4*)p;
            float4 u1 = *(const float4*)(p + 4);
            wa[0] = u0.x; wa[1] = u0.y; wa[2] = u0.z; wa[3] = u0.w;
            wa[4] = u1.x; wa[5] = u1.y; wa[6] = u1.z; wa[7] = u1.w;
        }

        bf16x8 ah[4], alo[4], bh[2], blo[2];
#pragma unroll
        for (int fm = 0; fm < 4; ++fm) {
            const int off = (wr + fm * 16 + l15) * LDK + lk;
            ah[fm]  = *(const bf16x8*)(Ah + off);
            alo[fm] = *(const bf16x8*)(Al + off);
        }
#pragma unroll
        for (int fn = 0; fn < 2; ++fn) {
            const int off = (wc + fn * 16 + l15) * LDK + lk;
            bh[fn]  = *(const bf16x8*)(Bh + off);
            blo[fn] = *(const bf16x8*)(Bl + off);
        }
#pragma unroll
        for (int fm = 0; fm < 4; ++fm)
#pragma unroll
            for (int fn = 0; fn < 2; ++fn) {
                acc[fm][fn] = __builtin_amdgcn_mfma_f32_16x16x32_bf16(
                    ah[fm], bh[fn], acc[fm][fn], 0, 0, 0);
                acc[fm][fn] = __builtin_amdgcn_mfma_f32_16x16x32_bf16(
                    ah[fm], blo[fn], acc[fm][fn], 0, 0, 0);
                acc[fm][fn] = __builtin_amdgcn_mfma_f32_16x16x32_bf16(
                    alo[fm], bh[fn], acc[fm][fn], 0, 0, 0);
            }
        __syncthreads();
    }

    // epilogue: C/D layout col = l&15, row = (l>>4)*4 + r
#pragma unroll
    for (int fm = 0; fm < 4; ++fm)
#pragma unroll
        for (int fn = 0; fn < 2; ++fn) {
            const int c = c0 + wc + fn * 16 + l15;
            const float bb = bias[c];
#pragma unroll
            for (int r = 0; r < 4; ++r) {
                const int m = m0 + wr + fm * 16 + (l >> 4) * 4 + r;
                const float v = (acc[fm][fn][r] + bb) * scale;
                if constexpr (OUTMODE == 0) {
                    Yf[(size_t)m * DMODEL + c] = v;
                } else {
                    const int b_ = m >> 10, n = m & 1023;
                    const int h = c >> 6, d = c & 63;
                    const size_t idx =
                        ((size_t)((b_ * NHEADS + h) * SEQ + n)) * HDIM + d;
                    if constexpr (OUTMODE == 1) {
                        Yf[idx] = v;
                    } else {
                        short hi, lo; split_bf16(v, hi, lo);
                        Yhi[idx] = hi; Ylo[idx] = lo;
                    }
                }
            }
        }
}

// ---------------------------------------------------------------------------
// Graph bias: attL[b][h][n][m] = dists[b][n][m][:8] . wg[h][:8]
// One block per (b,n); block-uniform early exit for masked rows.
// ---------------------------------------------------------------------------
__global__ __launch_bounds__(256) void graph_bias_kernel(
    const float* __restrict__ dists,
    const float* __restrict__ wg,
    const int* __restrict__ mask,
    float* __restrict__ attL)
{
    const int n = blockIdx.x & 1023;
    const int b = blockIdx.x >> 10;
    if (mask[b * SEQ + n]) return;

    __shared__ float wgs[NHEADS * DGRAPH];
    const int t = threadIdx.x;
    if (t < NHEADS * DGRAPH) wgs[t] = wg[t];
    __syncthreads();

    const int m = t * 4;
    const float* dp = dists + (((size_t)(b * SEQ + n)) * SEQ + m) * DGRAPH;
    float d[4][8];
#pragma unroll
    for (int i = 0; i < 8; ++i) {
        float4 v = *reinterpret_cast<const float4*>(dp + i * 4);
        d[i >> 1][(i & 1) * 4 + 0] = v.x; d[i >> 1][(i & 1) * 4 + 1] = v.y;
        d[i >> 1][(i & 1) * 4 + 2] = v.z; d[i >> 1][(i & 1) * 4 + 3] = v.w;
    }
#pragma unroll
    for (int h = 0; h < NHEADS; ++h) {
        float ov[4];
#pragma unroll
        for (int jm = 0; jm < 4; ++jm) {
            float s = 0.f;
#pragma unroll
            for (int p = 0; p < DGRAPH; ++p)
                s = fmaf(d[jm][p], wgs[h * DGRAPH + p], s);
            ov[jm] = s;
        }
        float4 o; o.x = ov[0]; o.y = ov[1]; o.z = ov[2]; o.w = ov[3];
        *reinterpret_cast<float4*>(
            attL + (((size_t)((b * NHEADS + h) * SEQ + n)) * SEQ + m)) = o;
    }
}

// ---------------------------------------------------------------------------
// MFMA QK^T + exp + row-sum: E = exp(bias + Qs.K) written to attL (unmasked
// rows only); per-row sums of E atomically accumulated into rowSum.
// Q staged pre-scaled & pre-split by proj. 128x128 tile, 4 waves (2x2),
// wave 64x64 = 4x4 fragments, K=64 in 2 ksteps. acc initialized from bias.
// ---------------------------------------------------------------------------
__global__ __launch_bounds__(256) void qk_mfma(
    const short* __restrict__ Qhi, const short* __restrict__ Qlo,
    const short* __restrict__ Khi, const short* __restrict__ Klo,
    const int* __restrict__ mask,
    float* __restrict__ attL,
    float* __restrict__ rowSum)
{
    constexpr int LDK = 72;
    __shared__ short sQh[128 * LDK];
    __shared__ short sQl[128 * LDK];
    __shared__ short sKh[128 * LDK];
    __shared__ short sKl[128 * LDK];
    __shared__ int maskS[128];

    const int t   = threadIdx.x;
    const int w   = t >> 6;
    const int l   = t & 63;
    const int l15 = l & 15;
    const int lk  = (l >> 4) * 8;
    const int m0  = blockIdx.x * 128;
    const int n0  = blockIdx.y * 128;
    const int bh  = blockIdx.z;
    const int b   = bh >> 4;

    if (t < 128) maskS[t] = mask[b * SEQ + n0 + t];

    // stage Q/K hi+lo tiles [128][64] bf16 -> padded LDS rows (LDK=72)
#pragma unroll
    for (int it = 0; it < 4; ++it) {
        const int f   = t + it * 256;
        const int row = f >> 3;
        const int c8  = f & 7;
        const size_t gq = ((size_t)bh * SEQ + n0 + row) * HDIM + c8 * 8;
        const size_t gk = ((size_t)bh * SEQ + m0 + row) * HDIM + c8 * 8;
        const int lo = row * LDK + c8 * 8;
        *(bf16x8*)(sQh + lo) = *(const bf16x8*)(Qhi + gq);
        *(bf16x8*)(sQl + lo) = *(const bf16x8*)(Qlo + gq);
        *(bf16x8*)(sKh + lo) = *(const bf16x8*)(Khi + gk);
        *(bf16x8*)(sKl + lo) = *(const bf16x8*)(Klo + gk);
    }

    const int nr = (w >> 1) * 64;   // wave row (n) base within tile
    const int mc = (w & 1) * 64;    // wave col (m) base within tile

    // acc init = graph bias tile (C/D layout: col=l15, row=(l>>4)*4+r)
    f32x4 acc[4][4];
    {
        const float* bb = attL + ((size_t)bh * SEQ + n0 + nr + (l >> 4) * 4) * SEQ
                          + m0 + mc + l15;
#pragma unroll
        for (int fm = 0; fm < 4; ++fm)
#pragma unroll
            for (int fn = 0; fn < 4; ++fn)
#pragma unroll
                for (int r = 0; r < 4; ++r)
                    acc[fm][fn][r] = bb[(size_t)(fm * 16 + r) * SEQ + fn * 16];
    }
    __syncthreads();

#pragma unroll
    for (int ks = 0; ks < 2; ++ks) {
        bf16x8 ah[4], alo[4], bhv[4], blo[4];
#pragma unroll
        for (int fm = 0; fm < 4; ++fm) {
            const int off = (nr + fm * 16 + l15) * LDK + ks * 32 + lk;
            ah[fm]  = *(const bf16x8*)(sQh + off);
            alo[fm] = *(const bf16x8*)(sQl + off);
        }
#pragma unroll
        for (int fn = 0; fn < 4; ++fn) {
            const int off = (mc + fn * 16 + l15) * LDK + ks * 32 + lk;
            bhv[fn] = *(const bf16x8*)(sKh + off);
            blo[fn] = *(const bf16x8*)(sKl + off);
        }
#pragma unroll
        for (int fm = 0; fm < 4; ++fm)
#pragma unroll
            for (int fn = 0; fn < 4; ++fn) {
                acc[fm][fn] = __builtin_amdgcn_mfma_f32_16x16x32_bf16(
                    ah[fm], bhv[fn], acc[fm][fn], 0, 0, 0);
                acc[fm][fn] = __builtin_amdgcn_mfma_f32_16x16x32_bf16(
                    ah[fm], blo[fn], acc[fm][fn], 0, 0, 0);
                acc[fm][fn] = __builtin_amdgcn_mfma_f32_16x16x32_bf16(
                    alo[fm], bhv[fn], acc[fm][fn], 0, 0, 0);
            }
    }

    // E = exp(S); store unmasked rows; shuffle-reduce row partials; atomic.
#pragma unroll
    for (int fm = 0; fm < 4; ++fm)
#pragma unroll
        for (int r = 0; r < 4; ++r) {
            const int nloc = nr + fm * 16 + (l >> 4) * 4 + r;
            const bool msk = maskS[nloc] != 0;
            float* rowp = attL + ((size_t)bh * SEQ + n0 + nloc) * SEQ + m0 + mc + l15;
            float s = 0.f;
#pragma unroll
            for (int fn = 0; fn < 4; ++fn) {
                const float e = __expf(acc[fm][fn][r]);
                s += e;
                if (!msk) rowp[fn * 16] = e;
            }
            s += __shfl_xor(s, 1); s += __shfl_xor(s, 2);
            s += __shfl_xor(s, 4); s += __shfl_xor(s, 8);
            if (!msk && l15 == 0)
                atomicAdd(rowSum + (size_t)bh * SEQ + n0 + nloc, s);
        }
}

// ---------------------------------------------------------------------------
// Normalize (E -> p in-place) + PV -> AO. 256 threads, 128 rows/block.
// No phase A: inv = 1/rowSum. Masked rows: p = 1/1024, no E read.
// ---------------------------------------------------------------------------
__global__ __launch_bounds__(256) void softmax_pv_kernel(
    float* __restrict__ attL,
    const float* __restrict__ VH,
    const int* __restrict__ mask,
    const float* __restrict__ rowSum,
    float* __restrict__ AO)
{
    __shared__ float pS[128 * 32];
    __shared__ float Vs[32][68];
    __shared__ float rowInv[128];
    __shared__ int   maskS[128];

    const int t    = threadIdx.x;
    const int n0   = blockIdx.x * 128;
    const int h    = blockIdx.y;
    const int b    = blockIdx.z;
    const int bh   = b * NHEADS + h;
    float* Lbase = attL + ((size_t)bh * SEQ + n0) * SEQ;

    if (t < 128) {
        const int mk = mask[b * SEQ + n0 + t];
        maskS[t] = mk;
        rowInv[t] = mk ? 0.f : 1.0f / rowSum[(size_t)bh * SEQ + n0 + t];
    }
    __syncthreads();

    const int TX = t & 7;             // d = TX*8 .. +7
    const int TY = t >> 3;            // rows TY*4 .. +3
    float acc[4][8];
#pragma unroll
    for (int i = 0; i < 4; ++i)
#pragma unroll
        for (int d = 0; d < 8; ++d) acc[i][d] = 0.f;

    float4 sreg[4];
#pragma unroll
    for (int i = 0; i < 4; ++i) sreg[i] = make_float4(0.f, 0.f, 0.f, 0.f);

    // prefetch chunk 0 (E values)
#pragma unroll
    for (int i = 0; i < 4; ++i) {
        int f4 = t + i * 256;
        int row = f4 >> 3, mq = f4 & 7;
        if (!maskS[row])
            sreg[i] = *reinterpret_cast<const float4*>(
                Lbase + (size_t)row * SEQ + mq * 4);
    }

    for (int mc = 0; mc < 32; ++mc) {
        // produce p: global att write + swizzled LDS write
#pragma unroll
        for (int i = 0; i < 4; ++i) {
            int f4 = t + i * 256;
            int row = f4 >> 3, mq = f4 & 7;
            float4 p4;
            if (maskS[row]) {
                p4.x = PCONST; p4.y = PCONST; p4.z = PCONST; p4.w = PCONST;
            } else {
                const float iv = rowInv[row];
                p4.x = sreg[i].x * iv;
                p4.y = sreg[i].y * iv;
                p4.z = sreg[i].z * iv;
                p4.w = sreg[i].w * iv;
            }
            *reinterpret_cast<float4*>(
                Lbase + (size_t)row * SEQ + mc * 32 + mq * 4) = p4;
            *reinterpret_cast<float4*>(
                pS + row * 32 + ((mq ^ ((row >> 3) & 7)) << 2)) = p4;
        }
        // stage V chunk [32][64]
#pragma unroll
        for (int i = 0; i < 2; ++i) {
            int f4 = t + i * 256;
            int m = f4 >> 4, dq = f4 & 15;
            *reinterpret_cast<float4*>(&Vs[m][dq * 4]) =
                *reinterpret_cast<const float4*>(
                    VH + ((size_t)bh * SEQ + mc * 32 + m) * HDIM + dq * 4);
        }
        __syncthreads();

        // prefetch next chunk's E under this chunk's FMAs
        if (mc + 1 < 32) {
#pragma unroll
            for (int i = 0; i < 4; ++i) {
                int f4 = t + i * 256;
                int row = f4 >> 3, mq = f4 & 7;
                if (!maskS[row])
                    sreg[i] = *reinterpret_cast<const float4*>(
                        Lbase + (size_t)row * SEQ + (mc + 1) * 32 + mq * 4);
            }
        }

        // micro: 4 rows x 8 d over 32 m
#pragma unroll
        for (int m4 = 0; m4 < 8; ++m4) {
            float pav[4][4];
#pragma unroll
            for (int i = 0; i < 4; ++i) {
                int row = TY * 4 + i;
                float4 p = *reinterpret_cast<const float4*>(
                    pS + row * 32 + ((m4 ^ ((row >> 3) & 7)) << 2));
                pav[i][0] = p.x; pav[i][1] = p.y; pav[i][2] = p.z; pav[i][3] = p.w;
            }
#pragma unroll
            for (int j = 0; j < 4; ++j) {
                float4 v0 = *reinterpret_cast<const float4*>(&Vs[m4 * 4 + j][TX * 8]);
                float4 v1 = *reinterpret_cast<const float4*>(&Vs[m4 * 4 + j][TX * 8 + 4]);
                float vb[8] = {v0.x, v0.y, v0.z, v0.w, v1.x, v1.y, v1.z, v1.w};
#pragma unroll
                for (int i = 0; i < 4; ++i)
#pragma unroll
                    for (int d = 0; d < 8; ++d)
                        acc[i][d] = fmaf(pav[i][j], vb[d], acc[i][d]);
            }
        }
        __syncthreads();
    }

#pragma unroll
    for (int i = 0; i < 4; ++i) {
        int n = n0 + TY * 4 + i;
        float4 o0, o1;
        o0.x = acc[i][0]; o0.y = acc[i][1]; o0.z = acc[i][2]; o0.w = acc[i][3];
        o1.x = acc[i][4]; o1.y = acc[i][5]; o1.z = acc[i][6]; o1.w = acc[i][7];
        float* op = AO + ((size_t)(b * SEQ + n)) * DMODEL + h * HDIM + TX * 8;
        *reinterpret_cast<float4*>(op)     = o0;
        *reinterpret_cast<float4*>(op + 4) = o1;
    }
}

// ---------------------------------------------------------------------------
extern "C" void kernel_launch(void* const* d_in, const int* in_sizes, int n_in,
                              void* d_out, int out_size, void* d_ws, size_t ws_size,
                              hipStream_t stream) {
    const float* q       = (const float*)d_in[0];
    const float* k       = (const float*)d_in[1];
    const float* v       = (const float*)d_in[2];
    const int*   mask    = (const int*)d_in[3];
    const float* dists   = (const float*)d_in[4];
    const float* weights = (const float*)d_in[5];
    const float* biases  = (const float*)d_in[6];
    const float* wg      = (const float*)d_in[7];

    float* out  = (float*)d_out;
    float* attL = out + (size_t)BATCH * SEQ * DMODEL;          // att region of d_out

    const size_t HSZ = (size_t)BATCH * NHEADS * SEQ * HDIM;    // 4,194,304
    short* Qhi = (short*)d_ws;
    short* Qlo = Qhi + HSZ;
    short* Khi = Qlo + HSZ;
    short* Klo = Khi + HSZ;
    float* VH  = (float*)(Klo + HSZ);
    float* AO  = (float*)d_ws;        // aliases Qhi+Qlo (dead after qk_mfma)
    float* rowSum = out;              // out[0:64K] — overwritten by final proj

    const int NROWS = BATCH * NHEADS * SEQ;                    // 65536
    zero_f32<<<(NROWS + 255) / 256, 256, 0, stream>>>(rowSum, NROWS);

    dim3 gProj(DMODEL / 64, (BATCH * SEQ) / 128);              // (16, 32)
    proj_mfma<2><<<gProj, 256, 0, stream>>>(q, weights, biases,
                                            nullptr, Qhi, Qlo, QK_SCALE);
    proj_mfma<2><<<gProj, 256, 0, stream>>>(k, weights + 1 * (size_t)DMODEL * DMODEL,
                                            biases + DMODEL, nullptr, Khi, Klo, 1.0f);
    proj_mfma<1><<<gProj, 256, 0, stream>>>(v, weights + 2 * (size_t)DMODEL * DMODEL,
                                            biases + 2 * DMODEL, VH, nullptr, nullptr, 1.0f);

    graph_bias_kernel<<<BATCH * SEQ, 256, 0, stream>>>(dists, wg, mask, attL);

    dim3 gQK(SEQ / 128, SEQ / 128, BATCH * NHEADS);            // (8, 8, 64)
    qk_mfma<<<gQK, 256, 0, stream>>>(Qhi, Qlo, Khi, Klo, mask, attL, rowSum);

    dim3 gPV(SEQ / 128, NHEADS, BATCH);                        // (8, 16, 4)
    softmax_pv_kernel<<<gPV, 256, 0, stream>>>(attL, VH, mask, rowSum, AO);

    proj_mfma<0><<<gProj, 256, 0, stream>>>(AO, weights + 3 * (size_t)DMODEL * DMODEL,
                                            biases + 3 * DMODEL, out, nullptr, nullptr, 1.0f);
}

// Round 8
// 437.766 us; speedup vs baseline: 3.1028x; 1.0892x over previous
//
#include <hip/hip_runtime.h>
#include <hip/hip_bf16.h>

#define SEQ      1024
#define BATCH    4
#define NHEADS   16
#define HDIM     64
#define DMODEL   1024
#define DGRAPH   8
#define QK_SCALE 0.125f
#define PCONST   0.0009765625f   /* 1/1024 exact */

typedef __attribute__((ext_vector_type(8))) short bf16x8;
typedef __attribute__((ext_vector_type(4))) short bf16x4;
typedef __attribute__((ext_vector_type(4))) float f32x4;

__device__ __forceinline__ void split_bf16(float x, short& hi, short& lo) {
    unsigned u = __float_as_uint(x);
    hi = (short)(u >> 16);                         // truncated high part
    float hf = __uint_as_float(u & 0xffff0000u);
    lo = (short)(__float_as_uint(x - hf) >> 16);   // residual, truncated
}

__global__ void zero_f32(float* p, int n) {
    int i = blockIdx.x * 256 + threadIdx.x;
    if (i < n) p[i] = 0.f;
}

// ---------------------------------------------------------------------------
// Split-bf16 MFMA projection: C[4096][1024] = X * W^T + bias (then *scale).
// OUTMODE 0: fp32 flat [m][DMODEL]                    (final projection)
// OUTMODE 2: bf16 hi/lo headsplit [b][h][n][d]        (Q pre-scaled, K)
// OUTMODE 3: bf16 hi/lo head-TRANSPOSED [b][h][d][n]  (V for PV MFMA B-op)
// BM=128, BN=64, BK=32, 4 waves (2x2). Proven r5/r6.
// ---------------------------------------------------------------------------
template<int OUTMODE>
__global__ __launch_bounds__(256) void proj_mfma(
    const float* __restrict__ X,
    const float* __restrict__ W,
    const float* __restrict__ bias,
    float* __restrict__ Yf,
    short* __restrict__ Yhi,
    short* __restrict__ Ylo,
    float scale)
{
    constexpr int LDK = 40;
    __shared__ short Ah[128 * LDK];
    __shared__ short Al[128 * LDK];
    __shared__ short Bh[64 * LDK];
    __shared__ short Bl[64 * LDK];

    const int t   = threadIdx.x;
    const int w   = t >> 6;
    const int l   = t & 63;
    const int l15 = l & 15;
    const int lk  = (l >> 4) * 8;
    const int m0  = blockIdx.y * 128;
    const int c0  = blockIdx.x * 64;
    const int wr  = (w >> 1) * 64;
    const int wc  = (w & 1) * 32;

    const int srow = t >> 2;
    const int skg  = t & 3;

    f32x4 acc[4][2];
#pragma unroll
    for (int i = 0; i < 4; ++i)
#pragma unroll
        for (int j = 0; j < 2; ++j) acc[i][j] = f32x4{0.f, 0.f, 0.f, 0.f};

    float xa[2][8];
    float wa[8];

#pragma unroll
    for (int i = 0; i < 2; ++i) {
        const float* p = X + (size_t)(m0 + srow + i * 64) * DMODEL + skg * 8;
        float4 u0 = *(const float4*)p;
        float4 u1 = *(const float4*)(p + 4);
        xa[i][0] = u0.x; xa[i][1] = u0.y; xa[i][2] = u0.z; xa[i][3] = u0.w;
        xa[i][4] = u1.x; xa[i][5] = u1.y; xa[i][6] = u1.z; xa[i][7] = u1.w;
    }
    {
        const float* p = W + (size_t)(c0 + srow) * DMODEL + skg * 8;
        float4 u0 = *(const float4*)p;
        float4 u1 = *(const float4*)(p + 4);
        wa[0] = u0.x; wa[1] = u0.y; wa[2] = u0.z; wa[3] = u0.w;
        wa[4] = u1.x; wa[5] = u1.y; wa[6] = u1.z; wa[7] = u1.w;
    }

    for (int kt = 0; kt < 32; ++kt) {
#pragma unroll
        for (int i = 0; i < 2; ++i) {
            bf16x8 hv, lv;
#pragma unroll
            for (int j = 0; j < 8; ++j) {
                short h, s; split_bf16(xa[i][j], h, s);
                hv[j] = h; lv[j] = s;
            }
            *(bf16x8*)(Ah + (srow + i * 64) * LDK + skg * 8) = hv;
            *(bf16x8*)(Al + (srow + i * 64) * LDK + skg * 8) = lv;
        }
        {
            bf16x8 hv, lv;
#pragma unroll
            for (int j = 0; j < 8; ++j) {
                short h, s; split_bf16(wa[j], h, s);
                hv[j] = h; lv[j] = s;
            }
            *(bf16x8*)(Bh + srow * LDK + skg * 8) = hv;
            *(bf16x8*)(Bl + srow * LDK + skg * 8) = lv;
        }
        __syncthreads();

        if (kt + 1 < 32) {
            const int k0 = (kt + 1) * 32;
#pragma unroll
            for (int i = 0; i < 2; ++i) {
                const float* p = X + (size_t)(m0 + srow + i * 64) * DMODEL + k0 + skg * 8;
                float4 u0 = *(const float4*)p;
                float4 u1 = *(const float4*)(p + 4);
                xa[i][0] = u0.x; xa[i][1] = u0.y; xa[i][2] = u0.z; xa[i][3] = u0.w;
                xa[i][4] = u1.x; xa[i][5] = u1.y; xa[i][6] = u1.z; xa[i][7] = u1.w;
            }
            const float* p = W + (size_t)(c0 + srow) * DMODEL + k0 + skg * 8;
            float4 u0 = *(const float4*)p;
            float4 u1 = *(const float4*)(p + 4);
            wa[0] = u0.x; wa[1] = u0.y; wa[2] = u0.z; wa[3] = u0.w;
            wa[4] = u1.x; wa[5] = u1.y; wa[6] = u1.z; wa[7] = u1.w;
        }

        bf16x8 ah[4], alo[4], bh[2], blo[2];
#pragma unroll
        for (int fm = 0; fm < 4; ++fm) {
            const int off = (wr + fm * 16 + l15) * LDK + lk;
            ah[fm]  = *(const bf16x8*)(Ah + off);
            alo[fm] = *(const bf16x8*)(Al + off);
        }
#pragma unroll
        for (int fn = 0; fn < 2; ++fn) {
            const int off = (wc + fn * 16 + l15) * LDK + lk;
            bh[fn]  = *(const bf16x8*)(Bh + off);
            blo[fn] = *(const bf16x8*)(Bl + off);
        }
#pragma unroll
        for (int fm = 0; fm < 4; ++fm)
#pragma unroll
            for (int fn = 0; fn < 2; ++fn) {
                acc[fm][fn] = __builtin_amdgcn_mfma_f32_16x16x32_bf16(
                    ah[fm], bh[fn], acc[fm][fn], 0, 0, 0);
                acc[fm][fn] = __builtin_amdgcn_mfma_f32_16x16x32_bf16(
                    ah[fm], blo[fn], acc[fm][fn], 0, 0, 0);
                acc[fm][fn] = __builtin_amdgcn_mfma_f32_16x16x32_bf16(
                    alo[fm], bh[fn], acc[fm][fn], 0, 0, 0);
            }
        __syncthreads();
    }

    // epilogue: C/D layout col = l&15, row = (l>>4)*4 + r
#pragma unroll
    for (int fm = 0; fm < 4; ++fm)
#pragma unroll
        for (int fn = 0; fn < 2; ++fn) {
            const int c = c0 + wc + fn * 16 + l15;
            const float bb = bias[c];
#pragma unroll
            for (int r = 0; r < 4; ++r) {
                const int m = m0 + wr + fm * 16 + (l >> 4) * 4 + r;
                const float v = (acc[fm][fn][r] + bb) * scale;
                if constexpr (OUTMODE == 0) {
                    Yf[(size_t)m * DMODEL + c] = v;
                } else {
                    const int b_ = m >> 10, n = m & 1023;
                    const int h = c >> 6, d = c & 63;
                    short hi, lo; split_bf16(v, hi, lo);
                    if constexpr (OUTMODE == 2) {
                        const size_t idx =
                            ((size_t)((b_ * NHEADS + h) * SEQ + n)) * HDIM + d;
                        Yhi[idx] = hi; Ylo[idx] = lo;
                    } else {  // OUTMODE 3: transposed [b][h][d][n]
                        const size_t idx =
                            ((size_t)((b_ * NHEADS + h) * HDIM + d)) * SEQ + n;
                        Yhi[idx] = hi; Ylo[idx] = lo;
                    }
                }
            }
        }
}

// ---------------------------------------------------------------------------
// Graph bias: attL[b][h][n][m] = dists[b][n][m][:8] . wg[h][:8]
// One block per (b,n); block-uniform early exit for masked rows.
// ---------------------------------------------------------------------------
__global__ __launch_bounds__(256) void graph_bias_kernel(
    const float* __restrict__ dists,
    const float* __restrict__ wg,
    const int* __restrict__ mask,
    float* __restrict__ attL)
{
    const int n = blockIdx.x & 1023;
    const int b = blockIdx.x >> 10;
    if (mask[b * SEQ + n]) return;

    __shared__ float wgs[NHEADS * DGRAPH];
    const int t = threadIdx.x;
    if (t < NHEADS * DGRAPH) wgs[t] = wg[t];
    __syncthreads();

    const int m = t * 4;
    const float* dp = dists + (((size_t)(b * SEQ + n)) * SEQ + m) * DGRAPH;
    float d[4][8];
#pragma unroll
    for (int i = 0; i < 8; ++i) {
        float4 v = *reinterpret_cast<const float4*>(dp + i * 4);
        d[i >> 1][(i & 1) * 4 + 0] = v.x; d[i >> 1][(i & 1) * 4 + 1] = v.y;
        d[i >> 1][(i & 1) * 4 + 2] = v.z; d[i >> 1][(i & 1) * 4 + 3] = v.w;
    }
#pragma unroll
    for (int h = 0; h < NHEADS; ++h) {
        float ov[4];
#pragma unroll
        for (int jm = 0; jm < 4; ++jm) {
            float s = 0.f;
#pragma unroll
            for (int p = 0; p < DGRAPH; ++p)
                s = fmaf(d[jm][p], wgs[h * DGRAPH + p], s);
            ov[jm] = s;
        }
        float4 o; o.x = ov[0]; o.y = ov[1]; o.z = ov[2]; o.w = ov[3];
        *reinterpret_cast<float4*>(
            attL + (((size_t)((b * NHEADS + h) * SEQ + n)) * SEQ + m)) = o;
    }
}

// ---------------------------------------------------------------------------
// MFMA QK^T + exp + row-sum. E = exp(bias + Qs.K) for unmasked rows only;
// masked rows: no bias read, no store, no atomic.
// ---------------------------------------------------------------------------
__global__ __launch_bounds__(256) void qk_mfma(
    const short* __restrict__ Qhi, const short* __restrict__ Qlo,
    const short* __restrict__ Khi, const short* __restrict__ Klo,
    const int* __restrict__ mask,
    float* __restrict__ attL,
    float* __restrict__ rowSum)
{
    constexpr int LDK = 72;
    __shared__ short sQh[128 * LDK];
    __shared__ short sQl[128 * LDK];
    __shared__ short sKh[128 * LDK];
    __shared__ short sKl[128 * LDK];
    __shared__ int maskS[128];

    const int t   = threadIdx.x;
    const int w   = t >> 6;
    const int l   = t & 63;
    const int l15 = l & 15;
    const int lk  = (l >> 4) * 8;
    const int m0  = blockIdx.x * 128;
    const int n0  = blockIdx.y * 128;
    const int bh  = blockIdx.z;
    const int b   = bh >> 4;

    if (t < 128) maskS[t] = mask[b * SEQ + n0 + t];

    // stage Q/K hi+lo tiles [128][64] bf16 -> padded LDS rows (LDK=72)
#pragma unroll
    for (int it = 0; it < 4; ++it) {
        const int f   = t + it * 256;
        const int row = f >> 3;
        const int c8  = f & 7;
        const size_t gq = ((size_t)bh * SEQ + n0 + row) * HDIM + c8 * 8;
        const size_t gk = ((size_t)bh * SEQ + m0 + row) * HDIM + c8 * 8;
        const int lo = row * LDK + c8 * 8;
        *(bf16x8*)(sQh + lo) = *(const bf16x8*)(Qhi + gq);
        *(bf16x8*)(sQl + lo) = *(const bf16x8*)(Qlo + gq);
        *(bf16x8*)(sKh + lo) = *(const bf16x8*)(Khi + gk);
        *(bf16x8*)(sKl + lo) = *(const bf16x8*)(Klo + gk);
    }
    __syncthreads();   // maskS + LDS tiles ready

    const int nr = (w >> 1) * 64;   // wave row (n) base within tile
    const int mc = (w & 1) * 64;    // wave col (m) base within tile

    // acc init = graph bias tile, masked rows -> 0 (no load, no HBM fetch)
    f32x4 acc[4][4];
    {
        const float* bb = attL + ((size_t)bh * SEQ + n0 + nr + (l >> 4) * 4) * SEQ
                          + m0 + mc + l15;
#pragma unroll
        for (int fm = 0; fm < 4; ++fm)
#pragma unroll
            for (int r = 0; r < 4; ++r) {
                const int nloc = nr + fm * 16 + (l >> 4) * 4 + r;
                const bool mk = maskS[nloc] != 0;
#pragma unroll
                for (int fn = 0; fn < 4; ++fn)
                    acc[fm][fn][r] =
                        mk ? 0.f : bb[(size_t)(fm * 16 + r) * SEQ + fn * 16];
            }
    }

#pragma unroll
    for (int ks = 0; ks < 2; ++ks) {
        bf16x8 ah[4], alo[4], bhv[4], blo[4];
#pragma unroll
        for (int fm = 0; fm < 4; ++fm) {
            const int off = (nr + fm * 16 + l15) * LDK + ks * 32 + lk;
            ah[fm]  = *(const bf16x8*)(sQh + off);
            alo[fm] = *(const bf16x8*)(sQl + off);
        }
#pragma unroll
        for (int fn = 0; fn < 4; ++fn) {
            const int off = (mc + fn * 16 + l15) * LDK + ks * 32 + lk;
            bhv[fn] = *(const bf16x8*)(sKh + off);
            blo[fn] = *(const bf16x8*)(sKl + off);
        }
#pragma unroll
        for (int fm = 0; fm < 4; ++fm)
#pragma unroll
            for (int fn = 0; fn < 4; ++fn) {
                acc[fm][fn] = __builtin_amdgcn_mfma_f32_16x16x32_bf16(
                    ah[fm], bhv[fn], acc[fm][fn], 0, 0, 0);
                acc[fm][fn] = __builtin_amdgcn_mfma_f32_16x16x32_bf16(
                    ah[fm], blo[fn], acc[fm][fn], 0, 0, 0);
                acc[fm][fn] = __builtin_amdgcn_mfma_f32_16x16x32_bf16(
                    alo[fm], bhv[fn], acc[fm][fn], 0, 0, 0);
            }
    }

    // E = exp(S); store unmasked rows; shuffle-reduce row partials; atomic.
#pragma unroll
    for (int fm = 0; fm < 4; ++fm)
#pragma unroll
        for (int r = 0; r < 4; ++r) {
            const int nloc = nr + fm * 16 + (l >> 4) * 4 + r;
            const bool msk = maskS[nloc] != 0;
            float* rowp = attL + ((size_t)bh * SEQ + n0 + nloc) * SEQ + m0 + mc + l15;
            float s = 0.f;
#pragma unroll
            for (int fn = 0; fn < 4; ++fn) {
                const float e = __expf(acc[fm][fn][r]);
                s += e;
                if (!msk) rowp[fn * 16] = e;
            }
            s += __shfl_xor(s, 1); s += __shfl_xor(s, 2);
            s += __shfl_xor(s, 4); s += __shfl_xor(s, 8);
            if (!msk && l15 == 0)
                atomicAdd(rowSum + (size_t)bh * SEQ + n0 + nloc, s);
        }
}

// ---------------------------------------------------------------------------
// Normalize (E -> p, written to att output) + PV via split-bf16 MFMA.
// Per (bh, 128 n-rows): 16 chunks of m=64. p split hi/lo into LDS (A-op);
// V pre-transposed+split by proj (VT[bh][d][n]) staged as [d][m] (B-op).
// 4 waves 2x2 over (128 n, 64 d); 48 MFMA : 24 ds_read_b128 per wave-chunk.
// ---------------------------------------------------------------------------
__global__ __launch_bounds__(256) void pv_mfma(
    float* __restrict__ attL,
    const short* __restrict__ VThi,
    const short* __restrict__ VTlo,
    const int* __restrict__ mask,
    const float* __restrict__ rowSum,
    float* __restrict__ AO)
{
    constexpr int LDP = 72;
    __shared__ short pHi[128 * LDP];
    __shared__ short pLo[128 * LDP];
    __shared__ short sVh[64 * LDP];
    __shared__ short sVl[64 * LDP];
    __shared__ float rowInv[128];
    __shared__ int   maskS[128];

    const int t   = threadIdx.x;
    const int w   = t >> 6;
    const int l   = t & 63;
    const int l15 = l & 15;
    const int lk  = (l >> 4) * 8;
    const int n0  = blockIdx.x * 128;
    const int h   = blockIdx.y;
    const int b   = blockIdx.z;
    const int bh  = b * NHEADS + h;
    float* Lbase = attL + ((size_t)bh * SEQ + n0) * SEQ;

    if (t < 128) {
        const int mk = mask[b * SEQ + n0 + t];
        maskS[t] = mk;
        rowInv[t] = mk ? 0.f : 1.0f / rowSum[(size_t)bh * SEQ + n0 + t];
    }
    __syncthreads();

    const int nr = (w >> 1) * 64;   // wave n base
    const int dc = (w & 1) * 32;    // wave d base

    f32x4 acc[4][2];
#pragma unroll
    for (int i = 0; i < 4; ++i)
#pragma unroll
        for (int j = 0; j < 2; ++j) acc[i][j] = f32x4{0.f, 0.f, 0.f, 0.f};

    // prefetch chunk 0 E values (8 float4/thread covering [128 n][64 m])
    float4 sreg[8];
#pragma unroll
    for (int i = 0; i < 8; ++i) sreg[i] = make_float4(0.f, 0.f, 0.f, 0.f);
#pragma unroll
    for (int i = 0; i < 8; ++i) {
        const int f4 = t + i * 256;
        const int row = f4 >> 4, mq = f4 & 15;
        if (!maskS[row])
            sreg[i] = *reinterpret_cast<const float4*>(
                Lbase + (size_t)row * SEQ + mq * 4);
    }

    for (int mc = 0; mc < 16; ++mc) {
        // produce p: global att write (fp32) + split hi/lo into LDS (A-op)
#pragma unroll
        for (int i = 0; i < 8; ++i) {
            const int f4 = t + i * 256;
            const int row = f4 >> 4, mq = f4 & 15;
            float4 p4;
            if (maskS[row]) {
                p4.x = PCONST; p4.y = PCONST; p4.z = PCONST; p4.w = PCONST;
            } else {
                const float iv = rowInv[row];
                p4.x = sreg[i].x * iv; p4.y = sreg[i].y * iv;
                p4.z = sreg[i].z * iv; p4.w = sreg[i].w * iv;
            }
            *reinterpret_cast<float4*>(
                Lbase + (size_t)row * SEQ + mc * 64 + mq * 4) = p4;
            bf16x4 hv, lv;
            short h0, s0, h1, s1, h2, s2, h3, s3;
            split_bf16(p4.x, h0, s0); split_bf16(p4.y, h1, s1);
            split_bf16(p4.z, h2, s2); split_bf16(p4.w, h3, s3);
            hv[0] = h0; hv[1] = h1; hv[2] = h2; hv[3] = h3;
            lv[0] = s0; lv[1] = s1; lv[2] = s2; lv[3] = s3;
            *(bf16x4*)(pHi + row * LDP + mq * 4) = hv;
            *(bf16x4*)(pLo + row * LDP + mq * 4) = lv;
        }
        // stage VT chunk [64 d][64 m] (bf16 hi/lo, already transposed)
#pragma unroll
        for (int i = 0; i < 2; ++i) {
            const int f = t + i * 256;
            const int d = f >> 3, m8 = f & 7;
            const size_t src = ((size_t)bh * HDIM + d) * SEQ + mc * 64 + m8 * 8;
            *(bf16x8*)(sVh + d * LDP + m8 * 8) = *(const bf16x8*)(VThi + src);
            *(bf16x8*)(sVl + d * LDP + m8 * 8) = *(const bf16x8*)(VTlo + src);
        }
        __syncthreads();

        // prefetch next chunk's E under this chunk's MFMAs
        if (mc + 1 < 16) {
#pragma unroll
            for (int i = 0; i < 8; ++i) {
                const int f4 = t + i * 256;
                const int row = f4 >> 4, mq = f4 & 15;
                if (!maskS[row])
                    sreg[i] = *reinterpret_cast<const float4*>(
                        Lbase + (size_t)row * SEQ + (mc + 1) * 64 + mq * 4);
            }
        }

        // MFMA: D[n][d] += p[n][m] * V[m][d]  (3-term split)
#pragma unroll
        for (int ks = 0; ks < 2; ++ks) {
            bf16x8 ah[4], alo[4], bhv[2], blo[2];
#pragma unroll
            for (int fm = 0; fm < 4; ++fm) {
                const int off = (nr + fm * 16 + l15) * LDP + ks * 32 + lk;
                ah[fm]  = *(const bf16x8*)(pHi + off);
                alo[fm] = *(const bf16x8*)(pLo + off);
            }
#pragma unroll
            for (int fn = 0; fn < 2; ++fn) {
                const int off = (dc + fn * 16 + l15) * LDP + ks * 32 + lk;
                bhv[fn] = *(const bf16x8*)(sVh + off);
                blo[fn] = *(const bf16x8*)(sVl + off);
            }
#pragma unroll
            for (int fm = 0; fm < 4; ++fm)
#pragma unroll
                for (int fn = 0; fn < 2; ++fn) {
                    acc[fm][fn] = __builtin_amdgcn_mfma_f32_16x16x32_bf16(
                        ah[fm], bhv[fn], acc[fm][fn], 0, 0, 0);
                    acc[fm][fn] = __builtin_amdgcn_mfma_f32_16x16x32_bf16(
                        ah[fm], blo[fn], acc[fm][fn], 0, 0, 0);
                    acc[fm][fn] = __builtin_amdgcn_mfma_f32_16x16x32_bf16(
                        alo[fm], bhv[fn], acc[fm][fn], 0, 0, 0);
                }
        }
        __syncthreads();
    }

    // epilogue: row = (l>>4)*4 + r (n), col = l15 (d)
#pragma unroll
    for (int fm = 0; fm < 4; ++fm)
#pragma unroll
        for (int fn = 0; fn < 2; ++fn) {
            const int dd = dc + fn * 16 + l15;
#pragma unroll
            for (int r = 0; r < 4; ++r) {
                const int n = n0 + nr + fm * 16 + (l >> 4) * 4 + r;
                AO[((size_t)(b * SEQ + n)) * DMODEL + h * HDIM + dd] =
                    acc[fm][fn][r];
            }
        }
}

// ---------------------------------------------------------------------------
extern "C" void kernel_launch(void* const* d_in, const int* in_sizes, int n_in,
                              void* d_out, int out_size, void* d_ws, size_t ws_size,
                              hipStream_t stream) {
    const float* q       = (const float*)d_in[0];
    const float* k       = (const float*)d_in[1];
    const float* v       = (const float*)d_in[2];
    const int*   mask    = (const int*)d_in[3];
    const float* dists   = (const float*)d_in[4];
    const float* weights = (const float*)d_in[5];
    const float* biases  = (const float*)d_in[6];
    const float* wg      = (const float*)d_in[7];

    float* out  = (float*)d_out;
    float* attL = out + (size_t)BATCH * SEQ * DMODEL;          // att region of d_out

    const size_t HSZ = (size_t)BATCH * NHEADS * SEQ * HDIM;    // 4,194,304
    short* Qhi  = (short*)d_ws;
    short* Qlo  = Qhi + HSZ;
    short* Khi  = Qlo + HSZ;
    short* Klo  = Khi + HSZ;
    short* VThi = Klo + HSZ;
    short* VTlo = VThi + HSZ;
    float* AO   = (float*)d_ws;       // aliases Qhi+Qlo (dead after qk_mfma)
    float* rowSum = out;              // out[0:64K] — overwritten by final proj

    const int NROWS = BATCH * NHEADS * SEQ;                    // 65536
    zero_f32<<<(NROWS + 255) / 256, 256, 0, stream>>>(rowSum, NROWS);

    dim3 gProj(DMODEL / 64, (BATCH * SEQ) / 128);              // (16, 32)
    proj_mfma<2><<<gProj, 256, 0, stream>>>(q, weights, biases,
                                            nullptr, Qhi, Qlo, QK_SCALE);
    proj_mfma<2><<<gProj, 256, 0, stream>>>(k, weights + 1 * (size_t)DMODEL * DMODEL,
                                            biases + DMODEL, nullptr, Khi, Klo, 1.0f);
    proj_mfma<3><<<gProj, 256, 0, stream>>>(v, weights + 2 * (size_t)DMODEL * DMODEL,
                                            biases + 2 * DMODEL, nullptr, VThi, VTlo, 1.0f);

    graph_bias_kernel<<<BATCH * SEQ, 256, 0, stream>>>(dists, wg, mask, attL);

    dim3 gQK(SEQ / 128, SEQ / 128, BATCH * NHEADS);            // (8, 8, 64)
    qk_mfma<<<gQK, 256, 0, stream>>>(Qhi, Qlo, Khi, Klo, mask, attL, rowSum);

    dim3 gPV(SEQ / 128, NHEADS, BATCH);                        // (8, 16, 4)
    pv_mfma<<<gPV, 256, 0, stream>>>(attL, VThi, VTlo, mask, rowSum, AO);

    proj_mfma<0><<<gProj, 256, 0, stream>>>(AO, weights + 3 * (size_t)DMODEL * DMODEL,
                                            biases + 3 * DMODEL, out, nullptr, nullptr, 1.0f);
}